// Round 1
// baseline (1341.041 us; speedup 1.0000x reference)
//
#include <hip/hip_runtime.h>
#include <math.h>

#define FDIM 512
#define HIDDIM 256

__device__ __forceinline__ float lrelu(float x, float s) { return x >= 0.0f ? x : s * x; }

__device__ __forceinline__ float blockReduceSum256(float v) {
  __shared__ float sm[4];
  int lane = threadIdx.x & 63, w = threadIdx.x >> 6;
#pragma unroll
  for (int o = 32; o; o >>= 1) v += __shfl_down(v, o, 64);
  __syncthreads();
  if (lane == 0) sm[w] = v;
  __syncthreads();
  return sm[0] + sm[1] + sm[2] + sm[3];
}

__device__ __forceinline__ float blockReduceMax256(float v) {
  __shared__ float sm[4];
  int lane = threadIdx.x & 63, w = threadIdx.x >> 6;
#pragma unroll
  for (int o = 32; o; o >>= 1) v = fmaxf(v, __shfl_down(v, o, 64));
  __syncthreads();
  if (lane == 0) sm[w] = v;
  __syncthreads();
  return fmaxf(fmaxf(sm[0], sm[1]), fmaxf(sm[2], sm[3]));
}

// ---------------- CSR build ----------------
__global__ __launch_bounds__(256) void k_count(const int* __restrict__ row, const int* __restrict__ col,
                                               int* __restrict__ cnt_r, int* __restrict__ cnt_c, int E) {
  int e = blockIdx.x * 256 + threadIdx.x;
  if (e < E) {
    atomicAdd(&cnt_r[row[e]], 1);
    atomicAdd(&cnt_c[col[e]], 1);
  }
}

__global__ __launch_bounds__(1024) void k_scan(const int* __restrict__ cnt, int* __restrict__ off, int n) {
  __shared__ int buf[1024];
  __shared__ int carry;
  int t = threadIdx.x;
  if (t == 0) carry = 0;
  __syncthreads();
  for (int base = 0; base < n; base += 1024) {
    int v = (base + t < n) ? cnt[base + t] : 0;
    buf[t] = v;
    __syncthreads();
    for (int s = 1; s < 1024; s <<= 1) {
      int x = (t >= s) ? buf[t - s] : 0;
      __syncthreads();
      buf[t] += x;
      __syncthreads();
    }
    if (base + t < n) off[base + t] = carry + buf[t] - v;  // exclusive
    __syncthreads();
    if (t == 0) carry += buf[1023];
    __syncthreads();
  }
  if (t == 0) off[n] = carry;
}

__global__ __launch_bounds__(256) void k_fill(const int* __restrict__ row, const int* __restrict__ col,
                                              const int* __restrict__ off_r, const int* __restrict__ off_c,
                                              int* __restrict__ cur_r, int* __restrict__ cur_c,
                                              int* __restrict__ csr_r, int* __restrict__ csr_c, int E) {
  int e = blockIdx.x * 256 + threadIdx.x;
  if (e < E) {
    int r = row[e], c = col[e];
    csr_r[off_r[r] + atomicAdd(&cur_r[r], 1)] = e;
    csr_c[off_c[c] + atomicAdd(&cur_c[c], 1)] = e;
  }
}

// ---------------- f32 tiled GEMM: C[Mr,Nc] = A[Mr,K] @ B[K,Nc] ----------------
// EPI: 0 = store; 1 = store lrelu(acc+bias,0.01); 2 = C += lrelu(acc+bias,0.01)
template <int EPI>
__global__ __launch_bounds__(256) void gemm_tile(const float* __restrict__ A, const float* __restrict__ B,
                                                 float* __restrict__ C, const float* __restrict__ bias,
                                                 int Mr, int K, int Nc) {
  __shared__ float As[16][64 + 4];  // transposed, +4 pad keeps 16B-aligned float4 rows, 2-way max conflicts
  __shared__ float Bs[16][64];
  int tid = threadIdx.x;
  int tx = tid & 15, ty = tid >> 4;
  int rowBase = blockIdx.x * 64;
  int colBase = blockIdx.y * 64;

  int ra = tid >> 2, ka = (tid & 3) << 2;   // A: 64 rows x 16 k, one float4/thread
  int kb = tid >> 4, nb = (tid & 15) << 2;  // B: 16 k x 64 cols, one float4/thread

  int garow = rowBase + ra;
  if (garow >= Mr) garow = Mr - 1;  // clamp; masked on store
  const float* Aptr = A + (size_t)garow * K + ka;
  const float* Bptr = B + (size_t)kb * Nc + colBase + nb;

  float acc[4][4] = {};
  for (int k0 = 0; k0 < K; k0 += 16) {
    float4 av = *(const float4*)(Aptr + k0);
    float4 bv = *(const float4*)(Bptr + (size_t)k0 * Nc);
    As[ka + 0][ra] = av.x;
    As[ka + 1][ra] = av.y;
    As[ka + 2][ra] = av.z;
    As[ka + 3][ra] = av.w;
    *(float4*)&Bs[kb][nb] = bv;
    __syncthreads();
#pragma unroll
    for (int k = 0; k < 16; ++k) {
      float4 a = *(const float4*)&As[k][ty << 2];
      float4 b = *(const float4*)&Bs[k][tx << 2];
      acc[0][0] = fmaf(a.x, b.x, acc[0][0]); acc[0][1] = fmaf(a.x, b.y, acc[0][1]);
      acc[0][2] = fmaf(a.x, b.z, acc[0][2]); acc[0][3] = fmaf(a.x, b.w, acc[0][3]);
      acc[1][0] = fmaf(a.y, b.x, acc[1][0]); acc[1][1] = fmaf(a.y, b.y, acc[1][1]);
      acc[1][2] = fmaf(a.y, b.z, acc[1][2]); acc[1][3] = fmaf(a.y, b.w, acc[1][3]);
      acc[2][0] = fmaf(a.z, b.x, acc[2][0]); acc[2][1] = fmaf(a.z, b.y, acc[2][1]);
      acc[2][2] = fmaf(a.z, b.z, acc[2][2]); acc[2][3] = fmaf(a.z, b.w, acc[2][3]);
      acc[3][0] = fmaf(a.w, b.x, acc[3][0]); acc[3][1] = fmaf(a.w, b.y, acc[3][1]);
      acc[3][2] = fmaf(a.w, b.z, acc[3][2]); acc[3][3] = fmaf(a.w, b.w, acc[3][3]);
    }
    __syncthreads();
  }

  int colo = colBase + (tx << 2);
  float4 b4 = make_float4(0.f, 0.f, 0.f, 0.f);
  if (EPI >= 1) b4 = *(const float4*)(bias + colo);
#pragma unroll
  for (int i = 0; i < 4; ++i) {
    int r = rowBase + (ty << 2) + i;
    if (r < Mr) {
      float4 v;
      v.x = acc[i][0]; v.y = acc[i][1]; v.z = acc[i][2]; v.w = acc[i][3];
      if (EPI >= 1) {
        v.x = lrelu(v.x + b4.x, 0.01f); v.y = lrelu(v.y + b4.y, 0.01f);
        v.z = lrelu(v.z + b4.z, 0.01f); v.w = lrelu(v.w + b4.w, 0.01f);
      }
      float* Cp = C + (size_t)r * Nc + colo;
      if (EPI == 2) {
        float4 o = *(const float4*)Cp;
        v.x += o.x; v.y += o.y; v.z += o.z; v.w += o.w;
      }
      *(float4*)Cp = v;
    }
  }
}

// ---------------- per-row dot with att vector (512 wide) ----------------
__global__ __launch_bounds__(256) void k_rowdot(const float* __restrict__ X, const float* __restrict__ att,
                                                float* __restrict__ out) {
  int r = blockIdx.x, t = threadIdx.x;
  const float* xr = X + (size_t)r * FDIM;
  float v = fmaf(xr[t], att[t], xr[t + 256] * att[t + 256]);
  v = blockReduceSum256(v);
  if (t == 0) out[r] = v;
}

// ---------------- grouped softmax over col segments ----------------
__global__ __launch_bounds__(256) void k_attn(const float* __restrict__ xa, const float* __restrict__ ea,
                                              const int* __restrict__ row, const int* __restrict__ csr_c,
                                              const int* __restrict__ off_c, float* __restrict__ alpha) {
  int m = blockIdx.x;
  int s = off_c[m], e_ = off_c[m + 1];
  float eam = ea[m];
  float mx = -3.402823466e38f;
  for (int j = s + threadIdx.x; j < e_; j += 256) {
    int e = csr_c[j];
    mx = fmaxf(mx, lrelu(xa[row[e]] + eam, 0.2f));
  }
  mx = blockReduceMax256(mx);
  float sum = 0.f;
  for (int j = s + threadIdx.x; j < e_; j += 256) {
    int e = csr_c[j];
    sum += expf(lrelu(xa[row[e]] + eam, 0.2f) - mx);
  }
  sum = blockReduceSum256(sum);
  float inv = 1.0f / fmaxf(sum, 1e-16f);
  for (int j = s + threadIdx.x; j < e_; j += 256) {
    int e = csr_c[j];
    alpha[e] = expf(lrelu(xa[row[e]] + eam, 0.2f) - mx) * inv;
  }
}

// ---------------- propagate 1: nodes -> hyperedges ----------------
__global__ __launch_bounds__(256) void k_prop_col(const float* __restrict__ xl, const float* __restrict__ alpha,
                                                  const int* __restrict__ row, const int* __restrict__ csr_c,
                                                  const int* __restrict__ off_c, float* __restrict__ ef) {
  int m = blockIdx.x;
  int s = off_c[m], e_ = off_c[m + 1];
  float binv = (e_ > s) ? 1.0f / (float)(e_ - s) : 0.0f;
  int f = threadIdx.x;
  float a0 = 0.f, a1 = 0.f;
  for (int j = s; j < e_; ++j) {
    int e = csr_c[j];
    float w = alpha[e] * binv;
    const float* xr = xl + (size_t)row[e] * FDIM;
    a0 = fmaf(w, xr[f], a0);
    a1 = fmaf(w, xr[f + 256], a1);
  }
  ef[(size_t)m * FDIM + f] = a0;
  ef[(size_t)m * FDIM + f + 256] = a1;
}

// ---------------- propagate 2: hyperedges -> nodes (+bias) ----------------
__global__ __launch_bounds__(256) void k_prop_row(const float* __restrict__ ef, const float* __restrict__ alpha,
                                                  const int* __restrict__ col, const int* __restrict__ csr_r,
                                                  const int* __restrict__ off_r, const float* __restrict__ bias,
                                                  float* __restrict__ out) {
  int n = blockIdx.x;
  int s = off_r[n], e_ = off_r[n + 1];
  float dinv = (e_ > s) ? 1.0f / (float)(e_ - s) : 0.0f;
  int f = threadIdx.x;
  float a0 = 0.f, a1 = 0.f;
  for (int j = s; j < e_; ++j) {
    int e = csr_r[j];
    float w = alpha[e] * dinv;
    const float* er = ef + (size_t)col[e] * FDIM;
    a0 = fmaf(w, er[f], a0);
    a1 = fmaf(w, er[f + 256], a1);
  }
  out[(size_t)n * FDIM + f] = a0 + bias[f];
  out[(size_t)n * FDIM + f + 256] = a1 + bias[f + 256];
}

// ---------------- GraphNorm ----------------
__global__ __launch_bounds__(256) void k_stats(const float* __restrict__ h, float* __restrict__ gsum,
                                               float* __restrict__ gsq, int N) {
  int t = threadIdx.x;
  float s0 = 0, q0 = 0, s1 = 0, q1 = 0;
  for (int r = blockIdx.x; r < N; r += gridDim.x) {
    float v0 = h[(size_t)r * FDIM + t];
    float v1 = h[(size_t)r * FDIM + 256 + t];
    s0 += v0; q0 = fmaf(v0, v0, q0);
    s1 += v1; q1 = fmaf(v1, v1, q1);
  }
  atomicAdd(&gsum[t], s0);
  atomicAdd(&gsq[t], q0);
  atomicAdd(&gsum[256 + t], s1);
  atomicAdd(&gsq[256 + t], q1);
}

__global__ __launch_bounds__(512) void k_nparam(const float* __restrict__ gsum, const float* __restrict__ gsq,
                                                const float* __restrict__ ms, const float* __restrict__ w,
                                                float* __restrict__ msm, float* __restrict__ scl, float invn) {
  int f = threadIdx.x;
  float mean = gsum[f] * invn;
  float ex2 = gsq[f] * invn;
  float m = ms[f];
  // var of (x - m*mean) = E[x^2] - (2m - m^2) * mean^2
  float var = ex2 - (2.0f * m - m * m) * mean * mean;
  scl[f] = w[f] / sqrtf(var + 1e-5f);
  msm[f] = m * mean;
}

__global__ __launch_bounds__(256) void k_napply(float* __restrict__ h, const float* __restrict__ msm,
                                                const float* __restrict__ scl, const float* __restrict__ b,
                                                int total4) {
  int i = blockIdx.x * 256 + threadIdx.x;
  if (i < total4) {
    int f4 = i & 127;  // 512/4 float4s per row
    float4 v = ((const float4*)h)[i];
    float4 mm = ((const float4*)msm)[f4];
    float4 sc = ((const float4*)scl)[f4];
    float4 bb = ((const float4*)b)[f4];
    v.x = lrelu((v.x - mm.x) * sc.x + bb.x, 0.01f);
    v.y = lrelu((v.y - mm.y) * sc.y + bb.y, 0.01f);
    v.z = lrelu((v.z - mm.z) * sc.z + bb.z, 0.01f);
    v.w = lrelu((v.w - mm.w) * sc.w + bb.w, 0.01f);
    ((float4*)h)[i] = v;
  }
}

// ---------------- classifier: logits = out1 @ cls_W + cls_b ----------------
__global__ __launch_bounds__(256) void k_cls(const float* __restrict__ out1, const float* __restrict__ W,
                                             const float* __restrict__ b, float* __restrict__ logits, int N) {
  __shared__ float Ws[512];
  int t = threadIdx.x;
  Ws[t] = W[t];
  Ws[256 + t] = W[256 + t];
  __syncthreads();
  int lane = t & 63, w = t >> 6;
  int r = blockIdx.x * 4 + w;
  if (r < N) {
    float a0 = 0.f, a1 = 0.f;
    for (int k = lane; k < 256; k += 64) {
      float v = out1[(size_t)r * 256 + k];
      a0 = fmaf(v, Ws[2 * k], a0);
      a1 = fmaf(v, Ws[2 * k + 1], a1);
    }
#pragma unroll
    for (int o = 32; o; o >>= 1) {
      a0 += __shfl_down(a0, o, 64);
      a1 += __shfl_down(a1, o, 64);
    }
    if (lane == 0) {
      logits[(size_t)r * 2] = a0 + b[0];
      logits[(size_t)r * 2 + 1] = a1 + b[1];
    }
  }
}

extern "C" void kernel_launch(void* const* d_in, const int* in_sizes, int n_in,
                              void* d_out, int out_size, void* d_ws, size_t ws_size,
                              hipStream_t stream) {
  const float* x      = (const float*)d_in[0];
  const int*   eidx   = (const int*)d_in[1];
  const float* eattr  = (const float*)d_in[2];
  const float* W1     = (const float*)d_in[3];
  const float* att1   = (const float*)d_in[4];
  const float* b1     = (const float*)d_in[5];
  const float* W2     = (const float*)d_in[6];
  const float* att2   = (const float*)d_in[7];
  const float* b2     = (const float*)d_in[8];
  const float* gn1_w  = (const float*)d_in[9];
  const float* gn1_b  = (const float*)d_in[10];
  const float* gn1_ms = (const float*)d_in[11];
  const float* gn2_w  = (const float*)d_in[12];
  const float* gn2_b  = (const float*)d_in[13];
  const float* gn2_ms = (const float*)d_in[14];
  const float* fc1_W  = (const float*)d_in[15];
  const float* fc1_b  = (const float*)d_in[16];
  const float* fc2_W  = (const float*)d_in[17];
  const float* fc2_b  = (const float*)d_in[18];
  const float* cls_W  = (const float*)d_in[19];
  const float* cls_b  = (const float*)d_in[20];
  float* logits = (float*)d_out;

  const int N = in_sizes[0] / FDIM;
  const int E = in_sizes[1] / 2;
  const int M = in_sizes[2] / FDIM;
  const int* row = eidx;
  const int* col = eidx + E;

  float* p = (float*)d_ws;
  float* xl = p;    p += (size_t)N * FDIM;
  float* h  = p;    p += (size_t)N * FDIM;
  float* el = p;    p += (size_t)M * FDIM;
  float* ef = p;    p += (size_t)M * FDIM;
  float* out1 = p;  p += (size_t)N * HIDDIM;
  float* xa = p;    p += N;
  float* ea = p;    p += M;
  float* alpha = p; p += E;
  float* gsum = p;  p += FDIM;
  float* gsq = p;   p += FDIM;
  float* msm = p;   p += FDIM;
  float* scl = p;   p += FDIM;
  int* ip = (int*)p;
  int* cnt_r = ip;  ip += N;
  int* cnt_c = ip;  ip += M;
  int* cur_r = ip;  ip += N;
  int* cur_c = ip;  ip += M;
  int* off_r = ip;  ip += N + 4;
  int* off_c = ip;  ip += M + 4;
  int* csr_r = ip;  ip += E;
  int* csr_c = ip;  ip += E;

  // zero degree counters + cursors (contiguous)
  hipMemsetAsync(cnt_r, 0, sizeof(int) * (size_t)(2 * (N + M)), stream);

  int gE = (E + 255) / 256;
  k_count<<<gE, 256, 0, stream>>>(row, col, cnt_r, cnt_c, E);
  k_scan<<<1, 1024, 0, stream>>>(cnt_r, off_r, N);
  k_scan<<<1, 1024, 0, stream>>>(cnt_c, off_c, M);
  k_fill<<<gE, 256, 0, stream>>>(row, col, off_r, off_c, cur_r, cur_c, csr_r, csr_c, E);

  dim3 blk(256);
  int gN64 = (N + 63) / 64, gM64 = (M + 63) / 64;
  int napply_grid = (N * FDIM / 4 + 255) / 256;

  // ---- conv1 ----
  gemm_tile<0><<<dim3(gN64, FDIM / 64), blk, 0, stream>>>(x, W1, xl, nullptr, N, FDIM, FDIM);
  gemm_tile<0><<<dim3(gM64, FDIM / 64), blk, 0, stream>>>(eattr, W1, el, nullptr, M, FDIM, FDIM);
  k_rowdot<<<N, 256, 0, stream>>>(xl, att1, xa);
  k_rowdot<<<M, 256, 0, stream>>>(el, att1 + FDIM, ea);
  k_attn<<<M, 256, 0, stream>>>(xa, ea, row, csr_c, off_c, alpha);
  k_prop_col<<<M, 256, 0, stream>>>(xl, alpha, row, csr_c, off_c, ef);
  k_prop_row<<<N, 256, 0, stream>>>(ef, alpha, col, csr_r, off_r, b1, h);
  // GraphNorm1 + leaky
  hipMemsetAsync(gsum, 0, sizeof(float) * 2 * FDIM, stream);
  k_stats<<<256, 256, 0, stream>>>(h, gsum, gsq, N);
  k_nparam<<<1, 512, 0, stream>>>(gsum, gsq, gn1_ms, gn1_w, msm, scl, 1.0f / (float)N);
  k_napply<<<napply_grid, 256, 0, stream>>>(h, msm, scl, gn1_b, N * FDIM / 4);
  // fc1
  gemm_tile<1><<<dim3(gN64, HIDDIM / 64), blk, 0, stream>>>(h, fc1_W, out1, fc1_b, N, FDIM, HIDDIM);

  // ---- conv2 (input = normed h) ----
  gemm_tile<0><<<dim3(gN64, FDIM / 64), blk, 0, stream>>>(h, W2, xl, nullptr, N, FDIM, FDIM);
  gemm_tile<0><<<dim3(gM64, FDIM / 64), blk, 0, stream>>>(eattr, W2, el, nullptr, M, FDIM, FDIM);
  k_rowdot<<<N, 256, 0, stream>>>(xl, att2, xa);
  k_rowdot<<<M, 256, 0, stream>>>(el, att2 + FDIM, ea);
  k_attn<<<M, 256, 0, stream>>>(xa, ea, row, csr_c, off_c, alpha);
  k_prop_col<<<M, 256, 0, stream>>>(xl, alpha, row, csr_c, off_c, ef);
  k_prop_row<<<N, 256, 0, stream>>>(ef, alpha, col, csr_r, off_r, b2, h);
  // GraphNorm2 + leaky
  hipMemsetAsync(gsum, 0, sizeof(float) * 2 * FDIM, stream);
  k_stats<<<256, 256, 0, stream>>>(h, gsum, gsq, N);
  k_nparam<<<1, 512, 0, stream>>>(gsum, gsq, gn2_ms, gn2_w, msm, scl, 1.0f / (float)N);
  k_napply<<<napply_grid, 256, 0, stream>>>(h, msm, scl, gn2_b, N * FDIM / 4);
  // fc2 accumulate into out1
  gemm_tile<2><<<dim3(gN64, HIDDIM / 64), blk, 0, stream>>>(h, fc2_W, out1, fc2_b, N, FDIM, HIDDIM);

  // classifier
  k_cls<<<(N + 3) / 4, 256, 0, stream>>>(out1, cls_W, cls_b, logits, N);
}

// Round 2
// 994.301 us; speedup vs baseline: 1.3487x; 1.3487x over previous
//
#include <hip/hip_runtime.h>
#include <math.h>

#define FDIM 512
#define HIDDIM 256

typedef __bf16 bf16x8 __attribute__((ext_vector_type(8)));
typedef float floatx4 __attribute__((ext_vector_type(4)));

__device__ __forceinline__ float lrelu(float x, float s) { return x >= 0.0f ? x : s * x; }

__device__ __forceinline__ float bf2f(unsigned int u) {
  union { float f; unsigned int i; } v; v.i = u << 16; return v.f;
}
__device__ __forceinline__ unsigned short f2bf(float f) {
  union { float f; unsigned int u; } v; v.f = f;
  unsigned int x = v.u;
  return (unsigned short)((x + 0x7fffu + ((x >> 16) & 1u)) >> 16);
}

__device__ __forceinline__ float waveReduceSum(float v) {
#pragma unroll
  for (int o = 32; o; o >>= 1) v += __shfl_down(v, o, 64);
  return v;
}

__device__ __forceinline__ float blockReduceSum256(float v) {
  __shared__ float sm[4];
  int lane = threadIdx.x & 63, w = threadIdx.x >> 6;
  v = waveReduceSum(v);
  __syncthreads();
  if (lane == 0) sm[w] = v;
  __syncthreads();
  return sm[0] + sm[1] + sm[2] + sm[3];
}

__device__ __forceinline__ float blockReduceMax256(float v) {
  __shared__ float sm[4];
  int lane = threadIdx.x & 63, w = threadIdx.x >> 6;
#pragma unroll
  for (int o = 32; o; o >>= 1) v = fmaxf(v, __shfl_down(v, o, 64));
  __syncthreads();
  if (lane == 0) sm[w] = v;
  __syncthreads();
  return fmaxf(fmaxf(sm[0], sm[1]), fmaxf(sm[2], sm[3]));
}

// ---------------- CSR build ----------------
__global__ __launch_bounds__(256) void k_count(const int* __restrict__ row, const int* __restrict__ col,
                                               int* __restrict__ cnt_r, int* __restrict__ cnt_c, int E) {
  int e = blockIdx.x * 256 + threadIdx.x;
  if (e < E) {
    atomicAdd(&cnt_r[row[e]], 1);
    atomicAdd(&cnt_c[col[e]], 1);
  }
}

__global__ __launch_bounds__(1024) void k_scan(const int* __restrict__ cnt, int* __restrict__ off, int n) {
  __shared__ int wsum[16];
  __shared__ int carry;
  int t = threadIdx.x, lane = t & 63, wv = t >> 6;
  if (t == 0) carry = 0;
  __syncthreads();
  for (int base = 0; base < n; base += 1024) {
    int v = (base + t < n) ? cnt[base + t] : 0;
    int x = v;
#pragma unroll
    for (int o = 1; o < 64; o <<= 1) {
      int y = __shfl_up(x, o, 64);
      if (lane >= o) x += y;
    }
    if (lane == 63) wsum[wv] = x;
    __syncthreads();
    if (wv == 0 && lane < 16) {
      int y = wsum[lane];
#pragma unroll
      for (int o = 1; o < 16; o <<= 1) {
        int z = __shfl_up(y, o, 64);
        if (lane >= o) y += z;
      }
      wsum[lane] = y;
    }
    __syncthreads();
    int wpre = (wv == 0) ? 0 : wsum[wv - 1];
    int incl = carry + wpre + x;
    if (base + t < n) off[base + t] = incl - v;
    __syncthreads();
    if (t == 1023) carry = incl;
    __syncthreads();
  }
  if (t == 0) off[n] = carry;
}

__global__ __launch_bounds__(256) void k_fill(const int* __restrict__ row, const int* __restrict__ col,
                                              const int* __restrict__ off_r, const int* __restrict__ off_c,
                                              int* __restrict__ cur_r, int* __restrict__ cur_c,
                                              int* __restrict__ csr_r, int* __restrict__ csr_c, int E) {
  int e = blockIdx.x * 256 + threadIdx.x;
  if (e < E) {
    int r = row[e], c = col[e];
    csr_r[off_r[r] + atomicAdd(&cur_r[r], 1)] = e;
    csr_c[off_c[c] + atomicAdd(&cur_c[c], 1)] = e;
  }
}

// ---------------- split f32 -> bf16 hi/lo ----------------
__global__ __launch_bounds__(256) void k_split(const float* __restrict__ A, unsigned short* __restrict__ hi,
                                               unsigned short* __restrict__ lo, int n4) {
  int i = blockIdx.x * 256 + threadIdx.x;
  if (i < n4) {
    float4 v = ((const float4*)A)[i];
    ushort4 h, l;
    h.x = f2bf(v.x); l.x = f2bf(v.x - bf2f(h.x));
    h.y = f2bf(v.y); l.y = f2bf(v.y - bf2f(h.y));
    h.z = f2bf(v.z); l.z = f2bf(v.z - bf2f(h.z));
    h.w = f2bf(v.w); l.w = f2bf(v.w - bf2f(h.w));
    ((ushort4*)hi)[i] = h;
    ((ushort4*)lo)[i] = l;
  }
}

// ---------------- weight prep: W[K,Nc] -> Bt_hi/lo[Nc,K] (transpose + split) ----------------
__global__ __launch_bounds__(256) void k_prep_w(const float* __restrict__ W, unsigned short* __restrict__ th,
                                                unsigned short* __restrict__ tl, int K, int Nc) {
  int n = blockIdx.x * 16 + (threadIdx.x & 15);
  int k = blockIdx.y * 16 + (threadIdx.x >> 4);
  float v = W[(size_t)k * Nc + n];
  unsigned short h = f2bf(v);
  unsigned short l = f2bf(v - bf2f(h));
  th[(size_t)n * K + k] = h;
  tl[(size_t)n * K + k] = l;
}

// ---------------- wv[k] = sum_f W[k,f] * att[f] ----------------
__global__ __launch_bounds__(256) void k_wv(const float* __restrict__ W, const float* __restrict__ att,
                                            float* __restrict__ wv) {
  int lane = threadIdx.x & 63, w = threadIdx.x >> 6;
  int k = blockIdx.x * 4 + w;
  float s = 0.f;
  for (int f = lane; f < FDIM; f += 64) s = fmaf(W[(size_t)k * FDIM + f], att[f], s);
  s = waveReduceSum(s);
  if (lane == 0) wv[k] = s;
}

// ---------------- ea[m] = sum_k eattr[m,k] * wv[k] ----------------
__global__ __launch_bounds__(256) void k_ea(const float* __restrict__ X, const float* __restrict__ wv,
                                            float* __restrict__ out, int Mr) {
  int lane = threadIdx.x & 63, w = threadIdx.x >> 6;
  int m = blockIdx.x * 4 + w;
  if (m < Mr) {
    float s = 0.f;
    for (int f = lane; f < FDIM; f += 64) s = fmaf(X[(size_t)m * FDIM + f], wv[f], s);
    s = waveReduceSum(s);
    if (lane == 0) out[m] = s;
  }
}

// ---------------- split-bf16 MFMA GEMM ----------------
// C[Mr,Nc] = A @ B, A given as hi/lo bf16 [Mr x K] row-major, B as hi/lo bf16 TRANSPOSED [Nc x K].
// EPI: 0 = store bf16(C) to Cb; 1 = Cf = lrelu(C+bias); 2 = Cf += lrelu(C+bias)
#define LDSK 40
template <int EPI>
__global__ __launch_bounds__(256, 1) void gemm_split(const unsigned short* __restrict__ Ahi,
                                                     const unsigned short* __restrict__ Alo,
                                                     const unsigned short* __restrict__ Bthi,
                                                     const unsigned short* __restrict__ Btlo,
                                                     float* __restrict__ Cf, unsigned short* __restrict__ Cb,
                                                     const float* __restrict__ bias, int Mr, int K, int Nc) {
  __shared__ unsigned short lds[4 * 128 * LDSK];  // Ah | Al | Bh | Bl, each 128 x LDSK
  int tid = threadIdx.x;
  int lane = tid & 63, w = tid >> 6;
  int wr = w >> 1, wc = w & 1;
  int rowB = blockIdx.x * 128;
  int colB = blockIdx.y * 128;

  // wave w stages array w
  const unsigned short* src = (w == 0) ? Ahi : (w == 1) ? Alo : (w == 2) ? Bthi : Btlo;
  int baseRow = (w < 2) ? rowB : colB;
  int maxRow = (w < 2) ? (Mr - 1) : (Nc - 1);
  int slr = lane >> 2, slc = lane & 3;  // 4 lanes per row, 8 bf16 each
  unsigned short* dstBase = &lds[w * 128 * LDSK];

  // precompute per-lane global row offsets for the 8 segments
  size_t gro[8];
#pragma unroll
  for (int seg = 0; seg < 8; ++seg) {
    int rg = baseRow + seg * 16 + slr;
    if (rg > maxRow) rg = maxRow;
    gro[seg] = (size_t)rg * K + slc * 8;
  }

  floatx4 zero4 = {0.f, 0.f, 0.f, 0.f};
  floatx4 acc[4][4];
#pragma unroll
  for (int i = 0; i < 4; ++i)
#pragma unroll
    for (int j = 0; j < 4; ++j) acc[i][j] = zero4;

  int fr = lane & 15, fq = lane >> 4;
  int offA = (wr * 64 + fr) * LDSK + fq * 8;
  int offB = (wc * 64 + fr) * LDSK + fq * 8;

  for (int k0 = 0; k0 < K; k0 += 32) {
#pragma unroll
    for (int seg = 0; seg < 8; ++seg) {
      float4 gv = *(const float4*)(src + gro[seg] + k0);
      *(float4*)(&dstBase[(seg * 16 + slr) * LDSK + slc * 8]) = gv;
    }
    __syncthreads();

    bf16x8 ah[4], al[4], bh[4], bl[4];
#pragma unroll
    for (int t = 0; t < 4; ++t) {
      int oa = offA + t * 16 * LDSK;
      int ob = offB + t * 16 * LDSK;
      ah[t] = *(const bf16x8*)(&lds[oa]);
      al[t] = *(const bf16x8*)(&lds[128 * LDSK + oa]);
      bh[t] = *(const bf16x8*)(&lds[2 * 128 * LDSK + ob]);
      bl[t] = *(const bf16x8*)(&lds[3 * 128 * LDSK + ob]);
    }
#pragma unroll
    for (int ti = 0; ti < 4; ++ti)
#pragma unroll
      for (int tj = 0; tj < 4; ++tj) {
        acc[ti][tj] = __builtin_amdgcn_mfma_f32_16x16x32_bf16(ah[ti], bh[tj], acc[ti][tj], 0, 0, 0);
        acc[ti][tj] = __builtin_amdgcn_mfma_f32_16x16x32_bf16(ah[ti], bl[tj], acc[ti][tj], 0, 0, 0);
        acc[ti][tj] = __builtin_amdgcn_mfma_f32_16x16x32_bf16(al[ti], bh[tj], acc[ti][tj], 0, 0, 0);
      }
    __syncthreads();
  }

  // epilogue: C[row = (lane>>4)*4 + reg (+16*ti +64*wr), col = lane&15 (+16*tj +64*wc)]
  int colL = colB + wc * 64 + (lane & 15);
  int rowL = rowB + wr * 64 + (lane >> 4) * 4;
#pragma unroll
  for (int tj = 0; tj < 4; ++tj) {
    int c = colL + tj * 16;
    float bb = (EPI >= 1) ? bias[c] : 0.f;
#pragma unroll
    for (int ti = 0; ti < 4; ++ti) {
      int r0 = rowL + ti * 16;
#pragma unroll
      for (int r = 0; r < 4; ++r) {
        int rr = r0 + r;
        if (rr < Mr) {
          float v = acc[ti][tj][r];
          if (EPI == 0) {
            Cb[(size_t)rr * Nc + c] = f2bf(v);
          } else if (EPI == 1) {
            Cf[(size_t)rr * Nc + c] = lrelu(v + bb, 0.01f);
          } else {
            Cf[(size_t)rr * Nc + c] += lrelu(v + bb, 0.01f);
          }
        }
      }
    }
  }
}

// ---------------- xa[r] = sum_f xl_bf16[r,f] * att[f] ----------------
__global__ __launch_bounds__(256) void k_rowdot_bf(const unsigned short* __restrict__ X,
                                                   const float* __restrict__ att, float* __restrict__ out) {
  int r = blockIdx.x, t = threadIdx.x;
  unsigned int u = ((const unsigned int*)(X + (size_t)r * FDIM))[t];
  float v = fmaf(bf2f(u & 0xffffu), att[2 * t], bf2f(u >> 16) * att[2 * t + 1]);
  v = blockReduceSum256(v);
  if (t == 0) out[r] = v;
}

// ---------------- grouped softmax over col segments ----------------
__global__ __launch_bounds__(256) void k_attn(const float* __restrict__ xa, const float* __restrict__ ea,
                                              const int* __restrict__ row, const int* __restrict__ csr_c,
                                              const int* __restrict__ off_c, float* __restrict__ alpha) {
  int m = blockIdx.x;
  int s = off_c[m], e_ = off_c[m + 1];
  float eam = ea[m];
  float mx = -3.402823466e38f;
  for (int j = s + threadIdx.x; j < e_; j += 256) {
    int e = csr_c[j];
    mx = fmaxf(mx, lrelu(xa[row[e]] + eam, 0.2f));
  }
  mx = blockReduceMax256(mx);
  float sum = 0.f;
  for (int j = s + threadIdx.x; j < e_; j += 256) {
    int e = csr_c[j];
    sum += expf(lrelu(xa[row[e]] + eam, 0.2f) - mx);
  }
  sum = blockReduceSum256(sum);
  float inv = 1.0f / fmaxf(sum, 1e-16f);
  for (int j = s + threadIdx.x; j < e_; j += 256) {
    int e = csr_c[j];
    alpha[e] = expf(lrelu(xa[row[e]] + eam, 0.2f) - mx) * inv;
  }
}

// ---------------- propagate 1: nodes -> hyperedges (bf16 gather, bf16 out) ----------------
__global__ __launch_bounds__(256) void k_prop_col(const unsigned short* __restrict__ xl,
                                                  const float* __restrict__ alpha, const int* __restrict__ row,
                                                  const int* __restrict__ csr_c, const int* __restrict__ off_c,
                                                  unsigned short* __restrict__ ef) {
  int m = blockIdx.x;
  int s = off_c[m], e_ = off_c[m + 1];
  float binv = (e_ > s) ? 1.0f / (float)(e_ - s) : 0.0f;
  int t = threadIdx.x;
  float a0 = 0.f, a1 = 0.f;
  for (int j = s; j < e_; ++j) {
    int e = csr_c[j];
    float wgt = alpha[e] * binv;
    unsigned int u = ((const unsigned int*)(xl + (size_t)row[e] * FDIM))[t];
    a0 = fmaf(wgt, bf2f(u & 0xffffu), a0);
    a1 = fmaf(wgt, bf2f(u >> 16), a1);
  }
  unsigned int o = (unsigned int)f2bf(a0) | ((unsigned int)f2bf(a1) << 16);
  ((unsigned int*)(ef + (size_t)m * FDIM))[t] = o;
}

// ---------------- propagate 2: hyperedges -> nodes, + bias, bf16 out ----------------
__global__ __launch_bounds__(256) void k_prop_row(const unsigned short* __restrict__ ef,
                                                  const float* __restrict__ alpha, const int* __restrict__ col,
                                                  const int* __restrict__ csr_r, const int* __restrict__ off_r,
                                                  const float* __restrict__ bias, unsigned short* __restrict__ hb) {
  int n = blockIdx.x;
  int s = off_r[n], e_ = off_r[n + 1];
  float dinv = (e_ > s) ? 1.0f / (float)(e_ - s) : 0.0f;
  int t = threadIdx.x;
  float a0 = 0.f, a1 = 0.f;
  for (int j = s; j < e_; ++j) {
    int e = csr_r[j];
    float wgt = alpha[e] * dinv;
    unsigned int u = ((const unsigned int*)(ef + (size_t)col[e] * FDIM))[t];
    a0 = fmaf(wgt, bf2f(u & 0xffffu), a0);
    a1 = fmaf(wgt, bf2f(u >> 16), a1);
  }
  a0 += bias[2 * t];
  a1 += bias[2 * t + 1];
  unsigned int o = (unsigned int)f2bf(a0) | ((unsigned int)f2bf(a1) << 16);
  ((unsigned int*)(hb + (size_t)n * FDIM))[t] = o;
}

// ---------------- GraphNorm stats (bf16 input) ----------------
__global__ __launch_bounds__(256) void k_stats(const unsigned short* __restrict__ hb, float* __restrict__ gsum,
                                               float* __restrict__ gsq, int N) {
  int t = threadIdx.x;
  float s0 = 0, q0 = 0, s1 = 0, q1 = 0;
  for (int r = blockIdx.x; r < N; r += gridDim.x) {
    unsigned int u = ((const unsigned int*)(hb + (size_t)r * FDIM))[t];
    float v0 = bf2f(u & 0xffffu), v1 = bf2f(u >> 16);
    s0 += v0; q0 = fmaf(v0, v0, q0);
    s1 += v1; q1 = fmaf(v1, v1, q1);
  }
  atomicAdd(&gsum[2 * t], s0);
  atomicAdd(&gsq[2 * t], q0);
  atomicAdd(&gsum[2 * t + 1], s1);
  atomicAdd(&gsq[2 * t + 1], q1);
}

__global__ __launch_bounds__(512) void k_nparam(const float* __restrict__ gsum, const float* __restrict__ gsq,
                                                const float* __restrict__ ms, const float* __restrict__ w,
                                                float* __restrict__ msm, float* __restrict__ scl, float invn) {
  int f = threadIdx.x;
  float mean = gsum[f] * invn;
  float ex2 = gsq[f] * invn;
  float m = ms[f];
  float var = ex2 - (2.0f * m - m * m) * mean * mean;
  scl[f] = w[f] / sqrtf(var + 1e-5f);
  msm[f] = m * mean;
}

// ---------------- GraphNorm apply + leaky + hi/lo split ----------------
__global__ __launch_bounds__(256) void k_napply(const unsigned short* __restrict__ hb,
                                                const float* __restrict__ msm, const float* __restrict__ scl,
                                                const float* __restrict__ b, unsigned short* __restrict__ hi,
                                                unsigned short* __restrict__ lo, int total2) {
  int i = blockIdx.x * 256 + threadIdx.x;
  if (i < total2) {
    int f2 = i & 255;  // uint index within row (2 feats)
    unsigned int u = ((const unsigned int*)hb)[i];
    float v0 = bf2f(u & 0xffffu), v1 = bf2f(u >> 16);
    int f0 = 2 * f2, f1 = 2 * f2 + 1;
    v0 = lrelu((v0 - msm[f0]) * scl[f0] + b[f0], 0.01f);
    v1 = lrelu((v1 - msm[f1]) * scl[f1] + b[f1], 0.01f);
    unsigned short h0 = f2bf(v0), h1 = f2bf(v1);
    unsigned short l0 = f2bf(v0 - bf2f(h0)), l1 = f2bf(v1 - bf2f(h1));
    ((unsigned int*)hi)[i] = (unsigned int)h0 | ((unsigned int)h1 << 16);
    ((unsigned int*)lo)[i] = (unsigned int)l0 | ((unsigned int)l1 << 16);
  }
}

// ---------------- classifier ----------------
__global__ __launch_bounds__(256) void k_cls(const float* __restrict__ out1, const float* __restrict__ W,
                                             const float* __restrict__ b, float* __restrict__ logits, int N) {
  __shared__ float Ws[512];
  int t = threadIdx.x;
  Ws[t] = W[t];
  Ws[256 + t] = W[256 + t];
  __syncthreads();
  int lane = t & 63, w = t >> 6;
  int r = blockIdx.x * 4 + w;
  if (r < N) {
    float a0 = 0.f, a1 = 0.f;
    for (int k = lane; k < 256; k += 64) {
      float v = out1[(size_t)r * 256 + k];
      a0 = fmaf(v, Ws[2 * k], a0);
      a1 = fmaf(v, Ws[2 * k + 1], a1);
    }
#pragma unroll
    for (int o = 32; o; o >>= 1) {
      a0 += __shfl_down(a0, o, 64);
      a1 += __shfl_down(a1, o, 64);
    }
    if (lane == 0) {
      logits[(size_t)r * 2] = a0 + b[0];
      logits[(size_t)r * 2 + 1] = a1 + b[1];
    }
  }
}

extern "C" void kernel_launch(void* const* d_in, const int* in_sizes, int n_in,
                              void* d_out, int out_size, void* d_ws, size_t ws_size,
                              hipStream_t stream) {
  const float* x      = (const float*)d_in[0];
  const int*   eidx   = (const int*)d_in[1];
  const float* eattr  = (const float*)d_in[2];
  const float* W1     = (const float*)d_in[3];
  const float* att1   = (const float*)d_in[4];
  const float* b1     = (const float*)d_in[5];
  const float* W2     = (const float*)d_in[6];
  const float* att2   = (const float*)d_in[7];
  const float* b2     = (const float*)d_in[8];
  const float* gn1_w  = (const float*)d_in[9];
  const float* gn1_b  = (const float*)d_in[10];
  const float* gn1_ms = (const float*)d_in[11];
  const float* gn2_w  = (const float*)d_in[12];
  const float* gn2_b  = (const float*)d_in[13];
  const float* gn2_ms = (const float*)d_in[14];
  const float* fc1_W  = (const float*)d_in[15];
  const float* fc1_b  = (const float*)d_in[16];
  const float* fc2_W  = (const float*)d_in[17];
  const float* fc2_b  = (const float*)d_in[18];
  const float* cls_W  = (const float*)d_in[19];
  const float* cls_b  = (const float*)d_in[20];
  float* logits = (float*)d_out;

  const int N = in_sizes[0] / FDIM;
  const int E = in_sizes[1] / 2;
  const int M = in_sizes[2] / FDIM;
  const int* row = eidx;
  const int* col = eidx + E;
  const size_t NS = (size_t)N * FDIM;
  const size_t MS = (size_t)M * FDIM;

  char* base = (char*)d_ws;
  auto alloc = [&](size_t bytes) { char* r = base; base += (bytes + 255) & ~(size_t)255; return r; };

  unsigned short* xhi = (unsigned short*)alloc(NS * 2);  // reused as hn_hi after napply
  unsigned short* xlo = (unsigned short*)alloc(NS * 2);  // reused as hn_lo
  unsigned short* xl  = (unsigned short*)alloc(NS * 2);  // GEMM output, bf16
  unsigned short* hb  = (unsigned short*)alloc(NS * 2);  // pre-norm h, bf16
  unsigned short* ef  = (unsigned short*)alloc(MS * 2);
  float* out1 = (float*)alloc((size_t)N * HIDDIM * 4);
  unsigned short* w1th = (unsigned short*)alloc(FDIM * FDIM * 2);
  unsigned short* w1tl = (unsigned short*)alloc(FDIM * FDIM * 2);
  unsigned short* w2th = (unsigned short*)alloc(FDIM * FDIM * 2);
  unsigned short* w2tl = (unsigned short*)alloc(FDIM * FDIM * 2);
  unsigned short* f1th = (unsigned short*)alloc(FDIM * HIDDIM * 2);
  unsigned short* f1tl = (unsigned short*)alloc(FDIM * HIDDIM * 2);
  unsigned short* f2th = (unsigned short*)alloc(FDIM * HIDDIM * 2);
  unsigned short* f2tl = (unsigned short*)alloc(FDIM * HIDDIM * 2);
  float* wv1 = (float*)alloc(FDIM * 4);
  float* wv2 = (float*)alloc(FDIM * 4);
  float* xa = (float*)alloc((size_t)N * 4);
  float* ea1 = (float*)alloc((size_t)M * 4);
  float* ea2 = (float*)alloc((size_t)M * 4);
  float* alpha = (float*)alloc((size_t)E * 4);
  float* gsum = (float*)alloc(FDIM * 4);
  float* gsq  = (float*)alloc(FDIM * 4);
  float* msm  = (float*)alloc(FDIM * 4);
  float* scl  = (float*)alloc(FDIM * 4);
  int* cnt_r = (int*)alloc((size_t)(2 * (N + M)) * 4);  // cnt_r | cnt_c | cur_r | cur_c contiguous
  int* cnt_c = cnt_r + N;
  int* cur_r = cnt_c + M;
  int* cur_c = cur_r + N;
  int* off_r = (int*)alloc((size_t)(N + 1) * 4);
  int* off_c = (int*)alloc((size_t)(M + 1) * 4);
  int* csr_r = (int*)alloc((size_t)E * 4);
  int* csr_c = (int*)alloc((size_t)E * 4);

  hipMemsetAsync(cnt_r, 0, sizeof(int) * (size_t)(2 * (N + M)), stream);

  int gE = (E + 255) / 256;
  k_count<<<gE, 256, 0, stream>>>(row, col, cnt_r, cnt_c, E);
  k_scan<<<1, 1024, 0, stream>>>(cnt_r, off_r, N);
  k_scan<<<1, 1024, 0, stream>>>(cnt_c, off_c, M);
  k_fill<<<gE, 256, 0, stream>>>(row, col, off_r, off_c, cur_r, cur_c, csr_r, csr_c, E);

  // precompute: x split, weight transposes/splits, attention matvecs
  k_split<<<(int)((NS / 4 + 255) / 256), 256, 0, stream>>>(x, xhi, xlo, (int)(NS / 4));
  k_prep_w<<<dim3(FDIM / 16, FDIM / 16), 256, 0, stream>>>(W1, w1th, w1tl, FDIM, FDIM);
  k_prep_w<<<dim3(FDIM / 16, FDIM / 16), 256, 0, stream>>>(W2, w2th, w2tl, FDIM, FDIM);
  k_prep_w<<<dim3(HIDDIM / 16, FDIM / 16), 256, 0, stream>>>(fc1_W, f1th, f1tl, FDIM, HIDDIM);
  k_prep_w<<<dim3(HIDDIM / 16, FDIM / 16), 256, 0, stream>>>(fc2_W, f2th, f2tl, FDIM, HIDDIM);
  k_wv<<<FDIM / 4, 256, 0, stream>>>(W1, att1 + FDIM, wv1);
  k_wv<<<FDIM / 4, 256, 0, stream>>>(W2, att2 + FDIM, wv2);
  k_ea<<<(M + 3) / 4, 256, 0, stream>>>(eattr, wv1, ea1, M);
  k_ea<<<(M + 3) / 4, 256, 0, stream>>>(eattr, wv2, ea2, M);

  int gN128 = (N + 127) / 128;
  int napply_grid = (int)((NS / 2 + 255) / 256);

  // ---- conv1 ----
  gemm_split<0><<<dim3(gN128, FDIM / 128), 256, 0, stream>>>(xhi, xlo, w1th, w1tl, nullptr, xl, nullptr, N, FDIM, FDIM);
  k_rowdot_bf<<<N, 256, 0, stream>>>(xl, att1, xa);
  k_attn<<<M, 256, 0, stream>>>(xa, ea1, row, csr_c, off_c, alpha);
  k_prop_col<<<M, 256, 0, stream>>>(xl, alpha, row, csr_c, off_c, ef);
  k_prop_row<<<N, 256, 0, stream>>>(ef, alpha, col, csr_r, off_r, b1, hb);
  hipMemsetAsync(gsum, 0, sizeof(float) * 2 * FDIM, stream);
  k_stats<<<256, 256, 0, stream>>>(hb, gsum, gsq, N);
  k_nparam<<<1, 512, 0, stream>>>(gsum, gsq, gn1_ms, gn1_w, msm, scl, 1.0f / (float)N);
  k_napply<<<napply_grid, 256, 0, stream>>>(hb, msm, scl, gn1_b, xhi, xlo, (int)(NS / 2));
  // fc1: out1 = lrelu(hn @ fc1_W + b)
  gemm_split<1><<<dim3(gN128, HIDDIM / 128), 256, 0, stream>>>(xhi, xlo, f1th, f1tl, out1, nullptr, fc1_b, N, FDIM, HIDDIM);

  // ---- conv2 ----
  gemm_split<0><<<dim3(gN128, FDIM / 128), 256, 0, stream>>>(xhi, xlo, w2th, w2tl, nullptr, xl, nullptr, N, FDIM, FDIM);
  k_rowdot_bf<<<N, 256, 0, stream>>>(xl, att2, xa);
  k_attn<<<M, 256, 0, stream>>>(xa, ea2, row, csr_c, off_c, alpha);
  k_prop_col<<<M, 256, 0, stream>>>(xl, alpha, row, csr_c, off_c, ef);
  k_prop_row<<<N, 256, 0, stream>>>(ef, alpha, col, csr_r, off_r, b2, hb);
  hipMemsetAsync(gsum, 0, sizeof(float) * 2 * FDIM, stream);
  k_stats<<<256, 256, 0, stream>>>(hb, gsum, gsq, N);
  k_nparam<<<1, 512, 0, stream>>>(gsum, gsq, gn2_ms, gn2_w, msm, scl, 1.0f / (float)N);
  k_napply<<<napply_grid, 256, 0, stream>>>(hb, msm, scl, gn2_b, xhi, xlo, (int)(NS / 2));
  // fc2: out1 += lrelu(hn2 @ fc2_W + b)
  gemm_split<2><<<dim3(gN128, HIDDIM / 128), 256, 0, stream>>>(xhi, xlo, f2th, f2tl, out1, nullptr, fc2_b, N, FDIM, HIDDIM);

  // classifier
  k_cls<<<(N + 3) / 4, 256, 0, stream>>>(out1, cls_W, cls_b, logits, N);
}

// Round 3
// 747.349 us; speedup vs baseline: 1.7944x; 1.3304x over previous
//
#include <hip/hip_runtime.h>
#include <math.h>

#define FDIM 512
#define HIDDIM 256

typedef __bf16 bf16x8 __attribute__((ext_vector_type(8)));
typedef float floatx4 __attribute__((ext_vector_type(4)));

__device__ __forceinline__ float lrelu(float x, float s) { return x >= 0.0f ? x : s * x; }

__device__ __forceinline__ float bf2f(unsigned int u) {
  union { float f; unsigned int i; } v; v.i = u << 16; return v.f;
}
__device__ __forceinline__ unsigned short f2bf(float f) {
  union { float f; unsigned int u; } v; v.f = f;
  unsigned int x = v.u;
  return (unsigned short)((x + 0x7fffu + ((x >> 16) & 1u)) >> 16);
}

__device__ __forceinline__ float waveReduceSum(float v) {
#pragma unroll
  for (int o = 32; o; o >>= 1) v += __shfl_down(v, o, 64);
  return v;
}

__device__ __forceinline__ float blockReduceSum256(float v) {
  __shared__ float sm[4];
  int lane = threadIdx.x & 63, w = threadIdx.x >> 6;
  v = waveReduceSum(v);
  __syncthreads();
  if (lane == 0) sm[w] = v;
  __syncthreads();
  return sm[0] + sm[1] + sm[2] + sm[3];
}

__device__ __forceinline__ float blockReduceMax256(float v) {
  __shared__ float sm[4];
  int lane = threadIdx.x & 63, w = threadIdx.x >> 6;
#pragma unroll
  for (int o = 32; o; o >>= 1) v = fmaxf(v, __shfl_down(v, o, 64));
  __syncthreads();
  if (lane == 0) sm[w] = v;
  __syncthreads();
  return fmaxf(fmaxf(sm[0], sm[1]), fmaxf(sm[2], sm[3]));
}

// ---------------- CSR build ----------------
__global__ __launch_bounds__(256) void k_count(const int* __restrict__ row, const int* __restrict__ col,
                                               int* __restrict__ cnt_r, int* __restrict__ cnt_c, int E) {
  int e = blockIdx.x * 256 + threadIdx.x;
  if (e < E) {
    atomicAdd(&cnt_r[row[e]], 1);
    atomicAdd(&cnt_c[col[e]], 1);
  }
}

__global__ __launch_bounds__(1024) void k_scan(const int* __restrict__ cnt, int* __restrict__ off, int n) {
  __shared__ int wsum[16];
  __shared__ int carry;
  int t = threadIdx.x, lane = t & 63, wv = t >> 6;
  if (t == 0) carry = 0;
  __syncthreads();
  for (int base = 0; base < n; base += 1024) {
    int v = (base + t < n) ? cnt[base + t] : 0;
    int x = v;
#pragma unroll
    for (int o = 1; o < 64; o <<= 1) {
      int y = __shfl_up(x, o, 64);
      if (lane >= o) x += y;
    }
    if (lane == 63) wsum[wv] = x;
    __syncthreads();
    if (wv == 0 && lane < 16) {
      int y = wsum[lane];
#pragma unroll
      for (int o = 1; o < 16; o <<= 1) {
        int z = __shfl_up(y, o, 64);
        if (lane >= o) y += z;
      }
      wsum[lane] = y;
    }
    __syncthreads();
    int wpre = (wv == 0) ? 0 : wsum[wv - 1];
    int incl = carry + wpre + x;
    if (base + t < n) off[base + t] = incl - v;
    __syncthreads();
    if (t == 1023) carry = incl;
    __syncthreads();
  }
  if (t == 0) off[n] = carry;
}

__global__ __launch_bounds__(256) void k_fill(const int* __restrict__ row, const int* __restrict__ col,
                                              const int* __restrict__ off_r, const int* __restrict__ off_c,
                                              int* __restrict__ cur_r, int* __restrict__ cur_c,
                                              int* __restrict__ csr_r, int* __restrict__ csr_c, int E) {
  int e = blockIdx.x * 256 + threadIdx.x;
  if (e < E) {
    int r = row[e], c = col[e];
    csr_r[off_r[r] + atomicAdd(&cur_r[r], 1)] = e;
    csr_c[off_c[c] + atomicAdd(&cur_c[c], 1)] = e;
  }
}

// rj[j] = row[csr_c[j]], cj[j] = col[csr_r[j]]  (kills double-indirection in hot loops)
__global__ __launch_bounds__(256) void k_gather_idx(const int* __restrict__ row, const int* __restrict__ col,
                                                    const int* __restrict__ csr_r, const int* __restrict__ csr_c,
                                                    int* __restrict__ rj, int* __restrict__ cj, int E) {
  int j = blockIdx.x * 256 + threadIdx.x;
  if (j < E) {
    rj[j] = row[csr_c[j]];
    cj[j] = col[csr_r[j]];
  }
}

// arj[j] = alpha_e[csr_r[j]]
__global__ __launch_bounds__(256) void k_perm_r(const float* __restrict__ alpha_e, const int* __restrict__ csr_r,
                                                float* __restrict__ arj, int E) {
  int j = blockIdx.x * 256 + threadIdx.x;
  if (j < E) arj[j] = alpha_e[csr_r[j]];
}

// ---------------- split f32 -> bf16 hi/lo ----------------
__global__ __launch_bounds__(256) void k_split(const float* __restrict__ A, unsigned short* __restrict__ hi,
                                               unsigned short* __restrict__ lo, int n4) {
  int i = blockIdx.x * 256 + threadIdx.x;
  if (i < n4) {
    float4 v = ((const float4*)A)[i];
    ushort4 h, l;
    h.x = f2bf(v.x); l.x = f2bf(v.x - bf2f(h.x));
    h.y = f2bf(v.y); l.y = f2bf(v.y - bf2f(h.y));
    h.z = f2bf(v.z); l.z = f2bf(v.z - bf2f(h.z));
    h.w = f2bf(v.w); l.w = f2bf(v.w - bf2f(h.w));
    ((ushort4*)hi)[i] = h;
    ((ushort4*)lo)[i] = l;
  }
}

// ---------------- weight prep: W[K,Nc] -> Bt_hi/lo[Nc,K] ----------------
__global__ __launch_bounds__(256) void k_prep_w(const float* __restrict__ W, unsigned short* __restrict__ th,
                                                unsigned short* __restrict__ tl, int K, int Nc) {
  int n = blockIdx.x * 16 + (threadIdx.x & 15);
  int k = blockIdx.y * 16 + (threadIdx.x >> 4);
  float v = W[(size_t)k * Nc + n];
  unsigned short h = f2bf(v);
  unsigned short l = f2bf(v - bf2f(h));
  th[(size_t)n * K + k] = h;
  tl[(size_t)n * K + k] = l;
}

// ---------------- wv[k] = sum_f W[k,f] * att[f] ----------------
__global__ __launch_bounds__(256) void k_wv(const float* __restrict__ W, const float* __restrict__ att,
                                            float* __restrict__ wv) {
  int lane = threadIdx.x & 63, w = threadIdx.x >> 6;
  int k = blockIdx.x * 4 + w;
  float s = 0.f;
  for (int f = lane; f < FDIM; f += 64) s = fmaf(W[(size_t)k * FDIM + f], att[f], s);
  s = waveReduceSum(s);
  if (lane == 0) wv[k] = s;
}

// ---------------- ea[m] = sum_k eattr[m,k] * wv[k] ----------------
__global__ __launch_bounds__(256) void k_ea(const float* __restrict__ X, const float* __restrict__ wv,
                                            float* __restrict__ out, int Mr) {
  int lane = threadIdx.x & 63, w = threadIdx.x >> 6;
  int m = blockIdx.x * 4 + w;
  if (m < Mr) {
    float s = 0.f;
    for (int f = lane; f < FDIM; f += 64) s = fmaf(X[(size_t)m * FDIM + f], wv[f], s);
    s = waveReduceSum(s);
    if (lane == 0) out[m] = s;
  }
}

// ---------------- split-bf16 MFMA GEMM ----------------
#define LDSK 40
template <int EPI>
__global__ __launch_bounds__(256, 1) void gemm_split(const unsigned short* __restrict__ Ahi,
                                                     const unsigned short* __restrict__ Alo,
                                                     const unsigned short* __restrict__ Bthi,
                                                     const unsigned short* __restrict__ Btlo,
                                                     float* __restrict__ Cf, unsigned short* __restrict__ Cb,
                                                     const float* __restrict__ bias, int Mr, int K, int Nc) {
  __shared__ unsigned short lds[4 * 128 * LDSK];
  int tid = threadIdx.x;
  int lane = tid & 63, w = tid >> 6;
  int wr = w >> 1, wc = w & 1;
  int rowB = blockIdx.x * 128;
  int colB = blockIdx.y * 128;

  const unsigned short* src = (w == 0) ? Ahi : (w == 1) ? Alo : (w == 2) ? Bthi : Btlo;
  int baseRow = (w < 2) ? rowB : colB;
  int maxRow = (w < 2) ? (Mr - 1) : (Nc - 1);
  int slr = lane >> 2, slc = lane & 3;
  unsigned short* dstBase = &lds[w * 128 * LDSK];

  size_t gro[8];
#pragma unroll
  for (int seg = 0; seg < 8; ++seg) {
    int rg = baseRow + seg * 16 + slr;
    if (rg > maxRow) rg = maxRow;
    gro[seg] = (size_t)rg * K + slc * 8;
  }

  floatx4 zero4 = {0.f, 0.f, 0.f, 0.f};
  floatx4 acc[4][4];
#pragma unroll
  for (int i = 0; i < 4; ++i)
#pragma unroll
    for (int j = 0; j < 4; ++j) acc[i][j] = zero4;

  int fr = lane & 15, fq = lane >> 4;
  int offA = (wr * 64 + fr) * LDSK + fq * 8;
  int offB = (wc * 64 + fr) * LDSK + fq * 8;

  for (int k0 = 0; k0 < K; k0 += 32) {
#pragma unroll
    for (int seg = 0; seg < 8; ++seg) {
      float4 gv = *(const float4*)(src + gro[seg] + k0);
      *(float4*)(&dstBase[(seg * 16 + slr) * LDSK + slc * 8]) = gv;
    }
    __syncthreads();

    bf16x8 ah[4], al[4], bh[4], bl[4];
#pragma unroll
    for (int t = 0; t < 4; ++t) {
      int oa = offA + t * 16 * LDSK;
      int ob = offB + t * 16 * LDSK;
      ah[t] = *(const bf16x8*)(&lds[oa]);
      al[t] = *(const bf16x8*)(&lds[128 * LDSK + oa]);
      bh[t] = *(const bf16x8*)(&lds[2 * 128 * LDSK + ob]);
      bl[t] = *(const bf16x8*)(&lds[3 * 128 * LDSK + ob]);
    }
#pragma unroll
    for (int ti = 0; ti < 4; ++ti)
#pragma unroll
      for (int tj = 0; tj < 4; ++tj) {
        acc[ti][tj] = __builtin_amdgcn_mfma_f32_16x16x32_bf16(ah[ti], bh[tj], acc[ti][tj], 0, 0, 0);
        acc[ti][tj] = __builtin_amdgcn_mfma_f32_16x16x32_bf16(ah[ti], bl[tj], acc[ti][tj], 0, 0, 0);
        acc[ti][tj] = __builtin_amdgcn_mfma_f32_16x16x32_bf16(al[ti], bh[tj], acc[ti][tj], 0, 0, 0);
      }
    __syncthreads();
  }

  int colL = colB + wc * 64 + (lane & 15);
  int rowL = rowB + wr * 64 + (lane >> 4) * 4;
#pragma unroll
  for (int tj = 0; tj < 4; ++tj) {
    int c = colL + tj * 16;
    float bb = (EPI >= 1) ? bias[c] : 0.f;
#pragma unroll
    for (int ti = 0; ti < 4; ++ti) {
      int r0 = rowL + ti * 16;
#pragma unroll
      for (int r = 0; r < 4; ++r) {
        int rr = r0 + r;
        if (rr < Mr) {
          float v = acc[ti][tj][r];
          if (EPI == 0) {
            Cb[(size_t)rr * Nc + c] = f2bf(v);
          } else if (EPI == 1) {
            Cf[(size_t)rr * Nc + c] = lrelu(v + bb, 0.01f);
          } else {
            Cf[(size_t)rr * Nc + c] += lrelu(v + bb, 0.01f);
          }
        }
      }
    }
  }
}

// ---------------- xa[r] = sum_f xl_bf16[r,f] * att[f] ----------------
__global__ __launch_bounds__(256) void k_rowdot_bf(const unsigned short* __restrict__ X,
                                                   const float* __restrict__ att, float* __restrict__ out) {
  int r = blockIdx.x, t = threadIdx.x;
  unsigned int u = ((const unsigned int*)(X + (size_t)r * FDIM))[t];
  float v = fmaf(bf2f(u & 0xffffu), att[2 * t], bf2f(u >> 16) * att[2 * t + 1]);
  v = blockReduceSum256(v);
  if (t == 0) out[r] = v;
}

// ---------------- grouped softmax; writes alpha in csr_c order (aj) AND by edge id (alpha_e) -------
__global__ __launch_bounds__(256) void k_attn(const float* __restrict__ xa, const float* __restrict__ ea,
                                              const int* __restrict__ rj, const int* __restrict__ csr_c,
                                              const int* __restrict__ off_c, float* __restrict__ aj,
                                              float* __restrict__ alpha_e) {
  int m = blockIdx.x;
  int s = off_c[m], e_ = off_c[m + 1];
  float eam = ea[m];
  int t = threadIdx.x;
  float mx = -3.402823466e38f;
  for (int j = s + t; j < e_; j += 256) {
    float a = lrelu(xa[rj[j]] + eam, 0.2f);
    aj[j] = a;
    mx = fmaxf(mx, a);
  }
  mx = blockReduceMax256(mx);
  float sum = 0.f;
  for (int j = s + t; j < e_; j += 256) sum += expf(aj[j] - mx);  // re-reads own writes
  sum = blockReduceSum256(sum);
  float inv = 1.0f / fmaxf(sum, 1e-16f);
  for (int j = s + t; j < e_; j += 256) {
    float a = expf(aj[j] - mx) * inv;
    aj[j] = a;
    alpha_e[csr_c[j]] = a;
  }
}

// ---------------- propagate: generic LDS-staged wave-split segment gather ----------------
// out_pack: uint per thread t = feats (2t, 2t+1), scale applied at end, optional bias.
__global__ __launch_bounds__(256) void k_prop_col(const unsigned short* __restrict__ xl,
                                                  const float* __restrict__ aj, const int* __restrict__ rj,
                                                  const int* __restrict__ off_c, unsigned short* __restrict__ ef) {
  int m = blockIdx.x;
  int s = off_c[m], e_ = off_c[m + 1];
  int cnt = e_ - s;
  __shared__ int sidx[512];
  __shared__ float swgt[512];
  __shared__ float pf[4][512];
  int t = threadIdx.x, lane = t & 63, w = t >> 6;
  float acc[8] = {0, 0, 0, 0, 0, 0, 0, 0};
  for (int base = 0; base < cnt; base += 512) {
    int n = min(512, cnt - base);
    for (int j = t; j < n; j += 256) {
      sidx[j] = rj[s + base + j];
      swgt[j] = aj[s + base + j];
    }
    __syncthreads();
    int j = w;
    for (; j + 8 <= n; j += 8) {
      int r0 = sidx[j], r1 = sidx[j + 4];
      float w0 = swgt[j], w1 = swgt[j + 4];
      bf16x8 v0 = *(const bf16x8*)(xl + (size_t)r0 * FDIM + lane * 8);
      bf16x8 v1 = *(const bf16x8*)(xl + (size_t)r1 * FDIM + lane * 8);
#pragma unroll
      for (int i = 0; i < 8; ++i) acc[i] = fmaf(w0, (float)v0[i], acc[i]);
#pragma unroll
      for (int i = 0; i < 8; ++i) acc[i] = fmaf(w1, (float)v1[i], acc[i]);
    }
    for (; j < n; j += 4) {
      int r = sidx[j];
      float wt = swgt[j];
      bf16x8 v = *(const bf16x8*)(xl + (size_t)r * FDIM + lane * 8);
#pragma unroll
      for (int i = 0; i < 8; ++i) acc[i] = fmaf(wt, (float)v[i], acc[i]);
    }
    __syncthreads();
  }
  float binv = cnt > 0 ? 1.0f / (float)cnt : 0.0f;
#pragma unroll
  for (int i = 0; i < 8; i += 2) *(float2*)&pf[w][lane * 8 + i] = make_float2(acc[i] * binv, acc[i + 1] * binv);
  __syncthreads();
  float2 r0 = ((const float2*)pf[0])[t], r1 = ((const float2*)pf[1])[t];
  float2 r2 = ((const float2*)pf[2])[t], r3 = ((const float2*)pf[3])[t];
  float a0 = r0.x + r1.x + r2.x + r3.x;
  float a1 = r0.y + r1.y + r2.y + r3.y;
  unsigned int o = (unsigned int)f2bf(a0) | ((unsigned int)f2bf(a1) << 16);
  ((unsigned int*)(ef + (size_t)m * FDIM))[t] = o;
}

__global__ __launch_bounds__(256) void k_prop_row(const unsigned short* __restrict__ ef,
                                                  const float* __restrict__ arj, const int* __restrict__ cj,
                                                  const int* __restrict__ off_r, const float* __restrict__ bias,
                                                  unsigned short* __restrict__ hb) {
  int nB = blockIdx.x;
  int s = off_r[nB], e_ = off_r[nB + 1];
  int cnt = e_ - s;
  __shared__ int sidx[512];
  __shared__ float swgt[512];
  __shared__ float pf[4][512];
  int t = threadIdx.x, lane = t & 63, w = t >> 6;
  float acc[8] = {0, 0, 0, 0, 0, 0, 0, 0};
  for (int base = 0; base < cnt; base += 512) {
    int n = min(512, cnt - base);
    for (int j = t; j < n; j += 256) {
      sidx[j] = cj[s + base + j];
      swgt[j] = arj[s + base + j];
    }
    __syncthreads();
    int j = w;
    for (; j + 8 <= n; j += 8) {
      int r0 = sidx[j], r1 = sidx[j + 4];
      float w0 = swgt[j], w1 = swgt[j + 4];
      bf16x8 v0 = *(const bf16x8*)(ef + (size_t)r0 * FDIM + lane * 8);
      bf16x8 v1 = *(const bf16x8*)(ef + (size_t)r1 * FDIM + lane * 8);
#pragma unroll
      for (int i = 0; i < 8; ++i) acc[i] = fmaf(w0, (float)v0[i], acc[i]);
#pragma unroll
      for (int i = 0; i < 8; ++i) acc[i] = fmaf(w1, (float)v1[i], acc[i]);
    }
    for (; j < n; j += 4) {
      int r = sidx[j];
      float wt = swgt[j];
      bf16x8 v = *(const bf16x8*)(ef + (size_t)r * FDIM + lane * 8);
#pragma unroll
      for (int i = 0; i < 8; ++i) acc[i] = fmaf(wt, (float)v[i], acc[i]);
    }
    __syncthreads();
  }
  float dinv = cnt > 0 ? 1.0f / (float)cnt : 0.0f;
#pragma unroll
  for (int i = 0; i < 8; i += 2) *(float2*)&pf[w][lane * 8 + i] = make_float2(acc[i] * dinv, acc[i + 1] * dinv);
  __syncthreads();
  float2 r0 = ((const float2*)pf[0])[t], r1 = ((const float2*)pf[1])[t];
  float2 r2 = ((const float2*)pf[2])[t], r3 = ((const float2*)pf[3])[t];
  float a0 = r0.x + r1.x + r2.x + r3.x + bias[2 * t];
  float a1 = r0.y + r1.y + r2.y + r3.y + bias[2 * t + 1];
  unsigned int o = (unsigned int)f2bf(a0) | ((unsigned int)f2bf(a1) << 16);
  ((unsigned int*)(hb + (size_t)nB * FDIM))[t] = o;
}

// ---------------- GraphNorm stats (bf16 input) ----------------
__global__ __launch_bounds__(256) void k_stats(const unsigned short* __restrict__ hb, float* __restrict__ gsum,
                                               float* __restrict__ gsq, int N) {
  int t = threadIdx.x;
  float s0 = 0, q0 = 0, s1 = 0, q1 = 0;
  for (int r = blockIdx.x; r < N; r += gridDim.x) {
    unsigned int u = ((const unsigned int*)(hb + (size_t)r * FDIM))[t];
    float v0 = bf2f(u & 0xffffu), v1 = bf2f(u >> 16);
    s0 += v0; q0 = fmaf(v0, v0, q0);
    s1 += v1; q1 = fmaf(v1, v1, q1);
  }
  atomicAdd(&gsum[2 * t], s0);
  atomicAdd(&gsq[2 * t], q0);
  atomicAdd(&gsum[2 * t + 1], s1);
  atomicAdd(&gsq[2 * t + 1], q1);
}

__global__ __launch_bounds__(512) void k_nparam(const float* __restrict__ gsum, const float* __restrict__ gsq,
                                                const float* __restrict__ ms, const float* __restrict__ w,
                                                float* __restrict__ msm, float* __restrict__ scl, float invn) {
  int f = threadIdx.x;
  float mean = gsum[f] * invn;
  float ex2 = gsq[f] * invn;
  float m = ms[f];
  float var = ex2 - (2.0f * m - m * m) * mean * mean;
  scl[f] = w[f] / sqrtf(var + 1e-5f);
  msm[f] = m * mean;
}

// ---------------- GraphNorm apply + leaky + hi/lo split ----------------
__global__ __launch_bounds__(256) void k_napply(const unsigned short* __restrict__ hb,
                                                const float* __restrict__ msm, const float* __restrict__ scl,
                                                const float* __restrict__ b, unsigned short* __restrict__ hi,
                                                unsigned short* __restrict__ lo, int total2) {
  int i = blockIdx.x * 256 + threadIdx.x;
  if (i < total2) {
    int f2 = i & 255;
    unsigned int u = ((const unsigned int*)hb)[i];
    float v0 = bf2f(u & 0xffffu), v1 = bf2f(u >> 16);
    int f0 = 2 * f2, f1 = 2 * f2 + 1;
    v0 = lrelu((v0 - msm[f0]) * scl[f0] + b[f0], 0.01f);
    v1 = lrelu((v1 - msm[f1]) * scl[f1] + b[f1], 0.01f);
    unsigned short h0 = f2bf(v0), h1 = f2bf(v1);
    unsigned short l0 = f2bf(v0 - bf2f(h0)), l1 = f2bf(v1 - bf2f(h1));
    ((unsigned int*)hi)[i] = (unsigned int)h0 | ((unsigned int)h1 << 16);
    ((unsigned int*)lo)[i] = (unsigned int)l0 | ((unsigned int)l1 << 16);
  }
}

// ---------------- classifier ----------------
__global__ __launch_bounds__(256) void k_cls(const float* __restrict__ out1, const float* __restrict__ W,
                                             const float* __restrict__ b, float* __restrict__ logits, int N) {
  __shared__ float Ws[512];
  int t = threadIdx.x;
  Ws[t] = W[t];
  Ws[256 + t] = W[256 + t];
  __syncthreads();
  int lane = t & 63, w = t >> 6;
  int r = blockIdx.x * 4 + w;
  if (r < N) {
    float a0 = 0.f, a1 = 0.f;
    for (int k = lane; k < 256; k += 64) {
      float v = out1[(size_t)r * 256 + k];
      a0 = fmaf(v, Ws[2 * k], a0);
      a1 = fmaf(v, Ws[2 * k + 1], a1);
    }
#pragma unroll
    for (int o = 32; o; o >>= 1) {
      a0 += __shfl_down(a0, o, 64);
      a1 += __shfl_down(a1, o, 64);
    }
    if (lane == 0) {
      logits[(size_t)r * 2] = a0 + b[0];
      logits[(size_t)r * 2 + 1] = a1 + b[1];
    }
  }
}

extern "C" void kernel_launch(void* const* d_in, const int* in_sizes, int n_in,
                              void* d_out, int out_size, void* d_ws, size_t ws_size,
                              hipStream_t stream) {
  const float* x      = (const float*)d_in[0];
  const int*   eidx   = (const int*)d_in[1];
  const float* eattr  = (const float*)d_in[2];
  const float* W1     = (const float*)d_in[3];
  const float* att1   = (const float*)d_in[4];
  const float* b1     = (const float*)d_in[5];
  const float* W2     = (const float*)d_in[6];
  const float* att2   = (const float*)d_in[7];
  const float* b2     = (const float*)d_in[8];
  const float* gn1_w  = (const float*)d_in[9];
  const float* gn1_b  = (const float*)d_in[10];
  const float* gn1_ms = (const float*)d_in[11];
  const float* gn2_w  = (const float*)d_in[12];
  const float* gn2_b  = (const float*)d_in[13];
  const float* gn2_ms = (const float*)d_in[14];
  const float* fc1_W  = (const float*)d_in[15];
  const float* fc1_b  = (const float*)d_in[16];
  const float* fc2_W  = (const float*)d_in[17];
  const float* fc2_b  = (const float*)d_in[18];
  const float* cls_W  = (const float*)d_in[19];
  const float* cls_b  = (const float*)d_in[20];
  float* logits = (float*)d_out;

  const int N = in_sizes[0] / FDIM;
  const int E = in_sizes[1] / 2;
  const int M = in_sizes[2] / FDIM;
  const int* row = eidx;
  const int* col = eidx + E;
  const size_t NS = (size_t)N * FDIM;
  const size_t MS = (size_t)M * FDIM;

  char* base = (char*)d_ws;
  auto alloc = [&](size_t bytes) { char* r = base; base += (bytes + 255) & ~(size_t)255; return r; };

  unsigned short* xhi = (unsigned short*)alloc(NS * 2);
  unsigned short* xlo = (unsigned short*)alloc(NS * 2);
  unsigned short* xl  = (unsigned short*)alloc(NS * 2);
  unsigned short* hb  = (unsigned short*)alloc(NS * 2);
  unsigned short* ef  = (unsigned short*)alloc(MS * 2);
  float* out1 = (float*)alloc((size_t)N * HIDDIM * 4);
  unsigned short* w1th = (unsigned short*)alloc(FDIM * FDIM * 2);
  unsigned short* w1tl = (unsigned short*)alloc(FDIM * FDIM * 2);
  unsigned short* w2th = (unsigned short*)alloc(FDIM * FDIM * 2);
  unsigned short* w2tl = (unsigned short*)alloc(FDIM * FDIM * 2);
  unsigned short* f1th = (unsigned short*)alloc(FDIM * HIDDIM * 2);
  unsigned short* f1tl = (unsigned short*)alloc(FDIM * HIDDIM * 2);
  unsigned short* f2th = (unsigned short*)alloc(FDIM * HIDDIM * 2);
  unsigned short* f2tl = (unsigned short*)alloc(FDIM * HIDDIM * 2);
  float* wv1 = (float*)alloc(FDIM * 4);
  float* wv2 = (float*)alloc(FDIM * 4);
  float* xa = (float*)alloc((size_t)N * 4);
  float* ea1 = (float*)alloc((size_t)M * 4);
  float* ea2 = (float*)alloc((size_t)M * 4);
  float* aj      = (float*)alloc((size_t)E * 4);
  float* arj     = (float*)alloc((size_t)E * 4);
  float* alpha_e = (float*)alloc((size_t)E * 4);
  float* gsum = (float*)alloc(FDIM * 4);
  float* gsq  = (float*)alloc(FDIM * 4);
  float* msm  = (float*)alloc(FDIM * 4);
  float* scl  = (float*)alloc(FDIM * 4);
  int* cnt_r = (int*)alloc((size_t)(2 * (N + M)) * 4);
  int* cnt_c = cnt_r + N;
  int* cur_r = cnt_c + M;
  int* cur_c = cur_r + N;
  int* off_r = (int*)alloc((size_t)(N + 1) * 4);
  int* off_c = (int*)alloc((size_t)(M + 1) * 4);
  int* csr_r = (int*)alloc((size_t)E * 4);
  int* csr_c = (int*)alloc((size_t)E * 4);
  int* rj = (int*)alloc((size_t)E * 4);
  int* cj = (int*)alloc((size_t)E * 4);

  hipMemsetAsync(cnt_r, 0, sizeof(int) * (size_t)(2 * (N + M)), stream);

  int gE = (E + 255) / 256;
  k_count<<<gE, 256, 0, stream>>>(row, col, cnt_r, cnt_c, E);
  k_scan<<<1, 1024, 0, stream>>>(cnt_r, off_r, N);
  k_scan<<<1, 1024, 0, stream>>>(cnt_c, off_c, M);
  k_fill<<<gE, 256, 0, stream>>>(row, col, off_r, off_c, cur_r, cur_c, csr_r, csr_c, E);
  k_gather_idx<<<gE, 256, 0, stream>>>(row, col, csr_r, csr_c, rj, cj, E);

  k_split<<<(int)((NS / 4 + 255) / 256), 256, 0, stream>>>(x, xhi, xlo, (int)(NS / 4));
  k_prep_w<<<dim3(FDIM / 16, FDIM / 16), 256, 0, stream>>>(W1, w1th, w1tl, FDIM, FDIM);
  k_prep_w<<<dim3(FDIM / 16, FDIM / 16), 256, 0, stream>>>(W2, w2th, w2tl, FDIM, FDIM);
  k_prep_w<<<dim3(HIDDIM / 16, FDIM / 16), 256, 0, stream>>>(fc1_W, f1th, f1tl, FDIM, HIDDIM);
  k_prep_w<<<dim3(HIDDIM / 16, FDIM / 16), 256, 0, stream>>>(fc2_W, f2th, f2tl, FDIM, HIDDIM);
  k_wv<<<FDIM / 4, 256, 0, stream>>>(W1, att1 + FDIM, wv1);
  k_wv<<<FDIM / 4, 256, 0, stream>>>(W2, att2 + FDIM, wv2);
  k_ea<<<(M + 3) / 4, 256, 0, stream>>>(eattr, wv1, ea1, M);
  k_ea<<<(M + 3) / 4, 256, 0, stream>>>(eattr, wv2, ea2, M);

  int gN128 = (N + 127) / 128;
  int napply_grid = (int)((NS / 2 + 255) / 256);

  // ---- conv1 ----
  gemm_split<0><<<dim3(gN128, FDIM / 128), 256, 0, stream>>>(xhi, xlo, w1th, w1tl, nullptr, xl, nullptr, N, FDIM, FDIM);
  k_rowdot_bf<<<N, 256, 0, stream>>>(xl, att1, xa);
  k_attn<<<M, 256, 0, stream>>>(xa, ea1, rj, csr_c, off_c, aj, alpha_e);
  k_perm_r<<<gE, 256, 0, stream>>>(alpha_e, csr_r, arj, E);
  k_prop_col<<<M, 256, 0, stream>>>(xl, aj, rj, off_c, ef);
  k_prop_row<<<N, 256, 0, stream>>>(ef, arj, cj, off_r, b1, hb);
  hipMemsetAsync(gsum, 0, sizeof(float) * 2 * FDIM, stream);
  k_stats<<<256, 256, 0, stream>>>(hb, gsum, gsq, N);
  k_nparam<<<1, 512, 0, stream>>>(gsum, gsq, gn1_ms, gn1_w, msm, scl, 1.0f / (float)N);
  k_napply<<<napply_grid, 256, 0, stream>>>(hb, msm, scl, gn1_b, xhi, xlo, (int)(NS / 2));
  gemm_split<1><<<dim3(gN128, HIDDIM / 128), 256, 0, stream>>>(xhi, xlo, f1th, f1tl, out1, nullptr, fc1_b, N, FDIM, HIDDIM);

  // ---- conv2 ----
  gemm_split<0><<<dim3(gN128, FDIM / 128), 256, 0, stream>>>(xhi, xlo, w2th, w2tl, nullptr, xl, nullptr, N, FDIM, FDIM);
  k_rowdot_bf<<<N, 256, 0, stream>>>(xl, att2, xa);
  k_attn<<<M, 256, 0, stream>>>(xa, ea2, rj, csr_c, off_c, aj, alpha_e);
  k_perm_r<<<gE, 256, 0, stream>>>(alpha_e, csr_r, arj, E);
  k_prop_col<<<M, 256, 0, stream>>>(xl, aj, rj, off_c, ef);
  k_prop_row<<<N, 256, 0, stream>>>(ef, arj, cj, off_r, b2, hb);
  hipMemsetAsync(gsum, 0, sizeof(float) * 2 * FDIM, stream);
  k_stats<<<256, 256, 0, stream>>>(hb, gsum, gsq, N);
  k_nparam<<<1, 512, 0, stream>>>(gsum, gsq, gn2_ms, gn2_w, msm, scl, 1.0f / (float)N);
  k_napply<<<napply_grid, 256, 0, stream>>>(hb, msm, scl, gn2_b, xhi, xlo, (int)(NS / 2));
  gemm_split<2><<<dim3(gN128, HIDDIM / 128), 256, 0, stream>>>(xhi, xlo, f2th, f2tl, out1, nullptr, fc2_b, N, FDIM, HIDDIM);

  k_cls<<<(N + 3) / 4, 256, 0, stream>>>(out1, cls_W, cls_b, logits, N);
}